// Round 1
// 492.154 us; speedup vs baseline: 1.2433x; 1.2433x over previous
//
#include <hip/hip_runtime.h>

// QuantizedLinear: out[M,N] = (x[M,K] @ W^T) * scale + bias, W[N,K] = q - zp
// M = 8192, N = 4096, K = 4096.
// GEMM: 256x256 tile, BK=64, 8 waves (2x4), 8-phase schedule with counted
// vmcnt (T3+T4), conflict-free LDS swizzle (T2, via pre-swizzled global
// source + swizzled ds_read), setprio around MFMA (T5), XCD block swizzle (T1).

typedef __bf16 bf16x8 __attribute__((ext_vector_type(8)));
typedef float  f32x4  __attribute__((ext_vector_type(4)));

// ---------------- conversion kernels (unchanged) ----------------

__global__ __launch_bounds__(256) void cvt_x_bf16(
    const float4* __restrict__ x, uint4* __restrict__ o, int n8) {
  int i = blockIdx.x * 256 + threadIdx.x;
  if (i >= n8) return;
  float4 a = x[2 * i];
  float4 b = x[2 * i + 1];
  union { __bf16 h[8]; uint4 u; } r;
  r.h[0] = (__bf16)a.x; r.h[1] = (__bf16)a.y;
  r.h[2] = (__bf16)a.z; r.h[3] = (__bf16)a.w;
  r.h[4] = (__bf16)b.x; r.h[5] = (__bf16)b.y;
  r.h[6] = (__bf16)b.z; r.h[7] = (__bf16)b.w;
  o[i] = r.u;
}

__global__ __launch_bounds__(256) void cvt_w_bf16(
    const int4* __restrict__ q, const int* __restrict__ zp,
    uint4* __restrict__ o, int n8) {
  int i = blockIdx.x * 256 + threadIdx.x;
  if (i >= n8) return;
  int z = zp[0];
  int4 a = q[2 * i];
  int4 b = q[2 * i + 1];
  union { __bf16 h[8]; uint4 u; } r;
  r.h[0] = (__bf16)(float)(a.x - z); r.h[1] = (__bf16)(float)(a.y - z);
  r.h[2] = (__bf16)(float)(a.z - z); r.h[3] = (__bf16)(float)(a.w - z);
  r.h[4] = (__bf16)(float)(b.x - z); r.h[5] = (__bf16)(float)(b.y - z);
  r.h[6] = (__bf16)(float)(b.z - z); r.h[7] = (__bf16)(float)(b.w - z);
  o[i] = r.u;
}

// ---------------- 256^2 8-phase GEMM ----------------
// LDS: A half-slots (128 rows x 64 cols bf16 = 16KB) at (d*2+h)*16384,
//      B half-slots at 65536 + (d*2+h)*16384. Total 128 KiB (dynamic).
// Half-slot layout: 16x32-subtiled + XOR swizzle:
//   byte(r,c) = ((r>>4)*2 + (c>>5))*1024 + [ (r&15)*64 + (c&31)*2 ] ^ (((r>>1)&3)<<4)
// global_load_lds writes LINEAR dest; source address carries the inverse
// (= same, involution) swizzle. ds_read applies the swizzle. This makes the
// b128 fragment reads 2-way (free) per 16-lane phase.

#define SLOT_A(d, h) ((((d) * 2 + (h)) << 14))
#define SLOT_B(d, h) ((1 << 16) + (((d) * 2 + (h)) << 14))

// Stage one half-tile (128 rows x 64 cols) of matrix at gbase into ldsOff.
// Per wave: 2 x global_load_lds(16B). Wave w covers rows w*16..w*16+15;
// instr i covers cols 32i..32i+31 (subtile w*2+i, 1KB each).
#define STAGE(gbase, ldsOff, h, s)                                            \
  do {                                                                        \
    const char* g_ = (gbase) + (size_t)(h) * 128 * K2 + (size_t)(s) * 128;    \
    __builtin_amdgcn_global_load_lds(                                         \
        (const __attribute__((address_space(1))) void*)(g_),                  \
        (__attribute__((address_space(3))) void*)(smem + (ldsOff) + wave * 2048), \
        16, 0, 0);                                                            \
    __builtin_amdgcn_global_load_lds(                                         \
        (const __attribute__((address_space(1))) void*)(g_ + 64),             \
        (__attribute__((address_space(3))) void*)(smem + (ldsOff) + wave * 2048 + 1024), \
        16, 0, 0);                                                            \
  } while (0)

#define LOAD_AF(d, qm)                                                        \
  do {                                                                        \
    _Pragma("unroll") for (int mf = 0; mf < 4; ++mf)                          \
    _Pragma("unroll") for (int kh = 0; kh < 2; ++kh)                          \
        af[mf][kh] = *(const bf16x8*)(smem + SLOT_A(d, qm) +                  \
            (((wr * 4 + mf) * 2 + kh) << 10) + innerOff);                     \
  } while (0)

#define LOAD_BF(dst, d, qn)                                                   \
  do {                                                                        \
    _Pragma("unroll") for (int nf = 0; nf < 2; ++nf)                          \
    _Pragma("unroll") for (int kh = 0; kh < 2; ++kh)                          \
        dst[nf][kh] = *(const bf16x8*)(smem + SLOT_B(d, qn) +                 \
            (((wc * 2 + nf) * 2 + kh) << 10) + innerOff);                     \
  } while (0)

#define MFMA_QUAD(qm, qn, BFR)                                                \
  do {                                                                        \
    __builtin_amdgcn_s_setprio(1);                                            \
    _Pragma("unroll") for (int mf = 0; mf < 4; ++mf)                          \
    _Pragma("unroll") for (int nf = 0; nf < 2; ++nf)                          \
    _Pragma("unroll") for (int kh = 0; kh < 2; ++kh)                          \
        acc[qm][qn][mf][nf] = __builtin_amdgcn_mfma_f32_16x16x32_bf16(        \
            af[mf][kh], BFR[nf][kh], acc[qm][qn][mf][nf], 0, 0, 0);           \
    __builtin_amdgcn_s_setprio(0);                                            \
  } while (0)

// One K-tile = 4 phases (block-C quadrants (0,0),(0,1),(1,1),(1,0)).
// Stage schedule (7-phase lead, 3 half-tiles in flight at checkpoints):
//   p1: Ab(t+1), p2: At(t+2), p3: Bt(t+2), p4: Bb(t+2); vmcnt(6) at p4.
// Safety: each stage targets a slot whose last LDS reader finished >=1
// barrier earlier (At:p1, Bt:p1, Bb:p2, Ab:p3).
#define TILE_BODY(t, d, e)                                                    \
  do {                                                                        \
    /* phase 1: quadrant (0,0) -- 12 ds_reads */                              \
    LOAD_AF(d, 0);                                                            \
    LOAD_BF(bf0, d, 0);                                                       \
    if ((t) + 1 < nt) STAGE(Abase, SLOT_A(e, 1), 1, (t) + 1);                 \
    __builtin_amdgcn_s_barrier();                                             \
    asm volatile("s_waitcnt lgkmcnt(0)");                                     \
    MFMA_QUAD(0, 0, bf0);                                                     \
    __builtin_amdgcn_s_barrier();                                             \
    /* phase 2: quadrant (0,1) -- 4 ds_reads, af reused */                    \
    LOAD_BF(bf1, d, 1);                                                       \
    if ((t) + 2 < nt) STAGE(Abase, SLOT_A(d, 0), 0, (t) + 2);                 \
    __builtin_amdgcn_s_barrier();                                             \
    asm volatile("s_waitcnt lgkmcnt(0)");                                     \
    MFMA_QUAD(0, 1, bf1);                                                     \
    __builtin_amdgcn_s_barrier();                                             \
    /* phase 3: quadrant (1,1) -- 8 ds_reads, bf1 reused */                   \
    LOAD_AF(d, 1);                                                            \
    if ((t) + 2 < nt) STAGE(Bbase, SLOT_B(d, 0), 0, (t) + 2);                 \
    __builtin_amdgcn_s_barrier();                                             \
    asm volatile("s_waitcnt lgkmcnt(0)");                                     \
    MFMA_QUAD(1, 1, bf1);                                                     \
    __builtin_amdgcn_s_barrier();                                             \
    /* phase 4: quadrant (1,0) -- 0 ds_reads, af & bf0 reused */              \
    if ((t) + 2 < nt) STAGE(Bbase, SLOT_B(d, 1), 1, (t) + 2);                 \
    __builtin_amdgcn_s_barrier();                                             \
    MFMA_QUAD(1, 0, bf0);                                                     \
    if ((t) + 2 < nt) { asm volatile("s_waitcnt vmcnt(6)"); }                 \
    else if ((t) + 1 < nt) { asm volatile("s_waitcnt vmcnt(0)"); }            \
    __builtin_amdgcn_s_barrier();                                             \
  } while (0)

__global__ __launch_bounds__(512, 2) void gemm256(
    const __bf16* __restrict__ A, const __bf16* __restrict__ Bw,
    const float* __restrict__ scale, const float* __restrict__ bias,
    float* __restrict__ C, int M, int N, int K) {
  extern __shared__ char smem[];

  const int tid  = threadIdx.x;
  const int wave = tid >> 6;
  const int lane = tid & 63;
  const int fr   = lane & 15;   // fragment row (A) / col (B,C)
  const int quad = lane >> 4;   // 0..3
  const int wr   = wave >> 2;   // 0..1 (M within quadrant)
  const int wc   = wave & 3;    // 0..3 (N within quadrant)

  // T1: XCD-aware swizzle. nwg = 512, divisible by 8 -> simple bijective form.
  const int nwg = gridDim.x;
  const int cpx = nwg >> 3;
  const int swzid = ((int)blockIdx.x & 7) * cpx + ((int)blockIdx.x >> 3);
  const int nbx = N >> 8;          // 16
  const int bx = swzid % nbx;
  const int by = swzid / nbx;

  const size_t K2 = (size_t)K << 1;  // row stride in bytes

  // staging per-lane source: row = wave*16 + lane>>2 within half,
  // col-byte within 64B = ((lane&3)<<4) ^ (((lane>>3)&3)<<4)  (inverse swizzle)
  const int rowLane = wave * 16 + (lane >> 2);
  const int colLane = ((lane & 3) << 4) ^ (((lane >> 3) & 3) << 4);
  const char* Abase = (const char*)A  + (size_t)(by * 256 + rowLane) * K2 + colLane;
  const char* Bbase = (const char*)Bw + (size_t)(bx * 256 + rowLane) * K2 + colLane;

  // ds_read per-lane inner offset (within 1KB subtile), swizzled:
  const int innerOff = (fr << 6) | ((quad << 4) ^ (((fr >> 1) & 3) << 4));

  f32x4 acc[2][2][4][2] = {};
  bf16x8 af[4][2], bf0[2][2], bf1[2][2];

  const int nt = K >> 6;  // 64 K-tiles

  // prologue: stage tile 0 fully + {At,Bt,Bb}(1); Ab(1) staged at p1(0).
  STAGE(Abase, SLOT_A(0, 0), 0, 0);
  STAGE(Abase, SLOT_A(0, 1), 1, 0);
  STAGE(Bbase, SLOT_B(0, 0), 0, 0);
  STAGE(Bbase, SLOT_B(0, 1), 1, 0);
  STAGE(Abase, SLOT_A(1, 0), 0, 1);
  STAGE(Bbase, SLOT_B(1, 0), 0, 1);
  STAGE(Bbase, SLOT_B(1, 1), 1, 1);
  asm volatile("s_waitcnt vmcnt(6)");   // tile 0 (oldest 8 loads) complete
  __builtin_amdgcn_s_barrier();

  for (int tt = 0; tt < nt; tt += 2) {
    TILE_BODY(tt, 0, 1);
    TILE_BODY(tt + 1, 1, 0);
  }

  // epilogue: C/D layout col = lane&15, row = quad*4 + reg (m89-verified)
  const float s = scale[0];
#pragma unroll
  for (int qm = 0; qm < 2; ++qm)
#pragma unroll
    for (int mf = 0; mf < 4; ++mf) {
      const int row0 = by * 256 + qm * 128 + wr * 64 + mf * 16 + quad * 4;
#pragma unroll
      for (int qn = 0; qn < 2; ++qn)
#pragma unroll
        for (int nf = 0; nf < 2; ++nf) {
          const int col = bx * 256 + qn * 128 + wc * 32 + nf * 16 + fr;
          const float bv = bias[col];
          float* cp = C + (size_t)row0 * N + col;
#pragma unroll
          for (int r = 0; r < 4; ++r)
            cp[(size_t)r * N] = s * acc[qm][qn][mf][nf][r] + bv;
        }
    }
}

// ---------------- launch ----------------

extern "C" void kernel_launch(void* const* d_in, const int* in_sizes, int n_in,
                              void* d_out, int out_size, void* d_ws, size_t ws_size,
                              hipStream_t stream) {
  const int M = 8192, N = 4096, K = 4096;

  const float* x    = (const float*)d_in[0];
  const int*   qw   = (const int*)d_in[1];
  const int*   zp   = (const int*)d_in[2];
  const float* sc   = (const float*)d_in[3];
  const float* bias = (const float*)d_in[4];
  float* out = (float*)d_out;

  __bf16* x_bf = (__bf16*)d_ws;
  __bf16* w_bf = (__bf16*)((char*)d_ws + (size_t)M * K * sizeof(__bf16));

  {
    int n8 = (M * K) / 8;
    cvt_x_bf16<<<n8 / 256, 256, 0, stream>>>((const float4*)x, (uint4*)x_bf, n8);
  }
  {
    int n8 = (N * K) / 8;
    cvt_w_bf16<<<n8 / 256, 256, 0, stream>>>((const int4*)qw, zp, (uint4*)w_bf, n8);
  }

  static bool attr_set = false;
  if (!attr_set) {
    hipFuncSetAttribute((const void*)gemm256,
                        hipFuncAttributeMaxDynamicSharedMemorySize, 131072);
    attr_set = true;
  }
  // grid: 512 workgroups = (N/256)*(M/256) = 16*32, 1-D for the XCD swizzle.
  gemm256<<<dim3(512), dim3(512), 131072, stream>>>(x_bf, w_bf, sc, bias, out, M, N, K);
}

// Round 2
// 482.755 us; speedup vs baseline: 1.2675x; 1.0195x over previous
//
#include <hip/hip_runtime.h>

// QuantizedLinear: out[M,N] = (x[M,K] @ W^T) * scale + bias, W[N,K] = q - zp
// M = 8192, N = 4096, K = 4096.
// GEMM: 256x256 tile, BK=64, 8 waves (2x4), 4-phase/K-tile schedule:
// single barrier per phase, compiler-managed lgkmcnt (reads+MFMA in same
// region), counted vmcnt(6) once per tile, conflict-free LDS swizzle via
// pre-swizzled global source, setprio around MFMA, XCD block swizzle.

typedef __bf16 bf16x8 __attribute__((ext_vector_type(8)));
typedef float  f32x4  __attribute__((ext_vector_type(4)));

// ---------------- conversion kernels (unchanged) ----------------

__global__ __launch_bounds__(256) void cvt_x_bf16(
    const float4* __restrict__ x, uint4* __restrict__ o, int n8) {
  int i = blockIdx.x * 256 + threadIdx.x;
  if (i >= n8) return;
  float4 a = x[2 * i];
  float4 b = x[2 * i + 1];
  union { __bf16 h[8]; uint4 u; } r;
  r.h[0] = (__bf16)a.x; r.h[1] = (__bf16)a.y;
  r.h[2] = (__bf16)a.z; r.h[3] = (__bf16)a.w;
  r.h[4] = (__bf16)b.x; r.h[5] = (__bf16)b.y;
  r.h[6] = (__bf16)b.z; r.h[7] = (__bf16)b.w;
  o[i] = r.u;
}

__global__ __launch_bounds__(256) void cvt_w_bf16(
    const int4* __restrict__ q, const int* __restrict__ zp,
    uint4* __restrict__ o, int n8) {
  int i = blockIdx.x * 256 + threadIdx.x;
  if (i >= n8) return;
  int z = zp[0];
  int4 a = q[2 * i];
  int4 b = q[2 * i + 1];
  union { __bf16 h[8]; uint4 u; } r;
  r.h[0] = (__bf16)(float)(a.x - z); r.h[1] = (__bf16)(float)(a.y - z);
  r.h[2] = (__bf16)(float)(a.z - z); r.h[3] = (__bf16)(float)(a.w - z);
  r.h[4] = (__bf16)(float)(b.x - z); r.h[5] = (__bf16)(float)(b.y - z);
  r.h[6] = (__bf16)(float)(b.z - z); r.h[7] = (__bf16)(float)(b.w - z);
  o[i] = r.u;
}

// ---------------- 256^2 GEMM, 4 phases / K-tile, 1 barrier / phase ----------
// LDS half-slot layout (128 rows x 64 bf16 cols = 16KB), 16x32-subtiled +
// XOR swizzle; global_load_lds writes linear, source pre-swizzled, ds_read
// swizzled (both-sides involution, rule #21).

#define SLOT_A(d, h) ((((d) * 2 + (h)) << 14))
#define SLOT_B(d, h) ((1 << 16) + (((d) * 2 + (h)) << 14))

#define STAGE(gbase, ldsOff, h, s)                                            \
  do {                                                                        \
    const char* g_ = (gbase) + (size_t)(h) * 128 * K2 + (size_t)(s) * 128;    \
    __builtin_amdgcn_global_load_lds(                                         \
        (const __attribute__((address_space(1))) void*)(g_),                  \
        (__attribute__((address_space(3))) void*)(smem + (ldsOff) + wave * 2048), \
        16, 0, 0);                                                            \
    __builtin_amdgcn_global_load_lds(                                         \
        (const __attribute__((address_space(1))) void*)(g_ + 64),             \
        (__attribute__((address_space(3))) void*)(smem + (ldsOff) + wave * 2048 + 1024), \
        16, 0, 0);                                                            \
  } while (0)

#define LOAD_AF(d, qm)                                                        \
  do {                                                                        \
    _Pragma("unroll") for (int mf = 0; mf < 4; ++mf)                          \
    _Pragma("unroll") for (int kh = 0; kh < 2; ++kh)                          \
        af[mf][kh] = *(const bf16x8*)(smem + SLOT_A(d, qm) +                  \
            (((wr * 4 + mf) * 2 + kh) << 10) + innerOff);                     \
  } while (0)

#define LOAD_BF(dst, d, qn)                                                   \
  do {                                                                        \
    _Pragma("unroll") for (int nf = 0; nf < 2; ++nf)                          \
    _Pragma("unroll") for (int kh = 0; kh < 2; ++kh)                          \
        dst[nf][kh] = *(const bf16x8*)(smem + SLOT_B(d, qn) +                 \
            (((wc * 2 + nf) * 2 + kh) << 10) + innerOff);                     \
  } while (0)

// kh OUTERMOST: 8 independent MFMAs, then 8 depending on 8-earlier (no
// back-to-back same-accumulator pairs).
#define MFMA_QUAD(qm, qn, BFR)                                                \
  do {                                                                        \
    __builtin_amdgcn_s_setprio(1);                                            \
    _Pragma("unroll") for (int kh = 0; kh < 2; ++kh)                          \
    _Pragma("unroll") for (int mf = 0; mf < 4; ++mf)                          \
    _Pragma("unroll") for (int nf = 0; nf < 2; ++nf)                          \
        acc[qm][qn][mf][nf] = __builtin_amdgcn_mfma_f32_16x16x32_bf16(        \
            af[mf][kh], BFR[nf][kh], acc[qm][qn][mf][nf], 0, 0, 0);           \
    __builtin_amdgcn_s_setprio(0);                                            \
  } while (0)

// One K-tile = 4 phases, ONE barrier per phase. Reads and MFMA share a
// region: compiler emits incremental lgkmcnt so first MFMAs start before all
// reads land. Safety: each phase's reads are fully consumed by its MFMAs
// (complete before the wave's barrier), every STAGE targets a slot whose last
// reader is >=1 phase earlier, vmcnt(6) precedes the barrier guarding
// next-tile reads.
#define TILE_BODY(t, d, e)                                                    \
  do {                                                                        \
    /* phase 1: Q(0,0), 12 reads */                                           \
    LOAD_AF(d, 0);                                                            \
    LOAD_BF(bf0, d, 0);                                                       \
    if ((t) + 1 < nt) STAGE(Abase, SLOT_A(e, 1), 1, (t) + 1);                 \
    MFMA_QUAD(0, 0, bf0);                                                     \
    __builtin_amdgcn_s_barrier();                                             \
    /* phase 2: Q(0,1), 4 reads */                                            \
    LOAD_BF(bf1, d, 1);                                                       \
    if ((t) + 2 < nt) STAGE(Abase, SLOT_A(d, 0), 0, (t) + 2);                 \
    MFMA_QUAD(0, 1, bf1);                                                     \
    __builtin_amdgcn_s_barrier();                                             \
    /* phase 3: Q(1,1), 8 reads */                                            \
    LOAD_AF(d, 1);                                                            \
    if ((t) + 2 < nt) STAGE(Bbase, SLOT_B(d, 0), 0, (t) + 2);                 \
    MFMA_QUAD(1, 1, bf1);                                                     \
    __builtin_amdgcn_s_barrier();                                             \
    /* phase 4: Q(1,0), 0 reads */                                            \
    if ((t) + 2 < nt) STAGE(Bbase, SLOT_B(d, 1), 1, (t) + 2);                 \
    MFMA_QUAD(1, 0, bf0);                                                     \
    if ((t) + 2 < nt) { asm volatile("s_waitcnt vmcnt(6)"); }                 \
    else if ((t) + 1 < nt) { asm volatile("s_waitcnt vmcnt(0)"); }            \
    __builtin_amdgcn_s_barrier();                                             \
  } while (0)

__global__ __launch_bounds__(512, 2) void gemm256(
    const __bf16* __restrict__ A, const __bf16* __restrict__ Bw,
    const float* __restrict__ scale, const float* __restrict__ bias,
    float* __restrict__ C) {
  extern __shared__ char smem[];

  constexpr int M = 8192, N = 4096, K = 4096;
  constexpr size_t K2 = (size_t)K * 2;  // row stride in bytes
  (void)M;

  const int tid  = threadIdx.x;
  const int wave = tid >> 6;
  const int lane = tid & 63;
  const int fr   = lane & 15;   // fragment row (A) / col (B,C)
  const int quad = lane >> 4;   // 0..3
  const int wr   = wave >> 2;   // 0..1 (M within quadrant)
  const int wc   = wave & 3;    // 0..3 (N within quadrant)

  // T1: XCD swizzle, nwg = 512 (divisible by 8).
  const int nwg = gridDim.x;
  const int cpx = nwg >> 3;
  const int swzid = ((int)blockIdx.x & 7) * cpx + ((int)blockIdx.x >> 3);
  const int nbx = N >> 8;          // 16
  const int bx = swzid % nbx;
  const int by = swzid / nbx;

  // staging per-lane source: row = wave*16 + lane>>2 within half,
  // col-byte = ((lane&3)<<4) ^ (((lane>>3)&3)<<4)  (inverse swizzle)
  const int rowLane = wave * 16 + (lane >> 2);
  const int colLane = ((lane & 3) << 4) ^ (((lane >> 3) & 3) << 4);
  const char* Abase = (const char*)A  + (size_t)(by * 256 + rowLane) * K2 + colLane;
  const char* Bbase = (const char*)Bw + (size_t)(bx * 256 + rowLane) * K2 + colLane;

  // ds_read per-lane inner offset (within 1KB subtile), swizzled:
  const int innerOff = (fr << 6) | ((quad << 4) ^ (((fr >> 1) & 3) << 4));

  f32x4 acc[2][2][4][2] = {};
  bf16x8 af[4][2], bf0[2][2], bf1[2][2];

  const int nt = K >> 6;  // 64 K-tiles

  // prologue: stage tile 0 fully + {At,Bt,Bb}(1); Ab(1) staged at p1(0).
  STAGE(Abase, SLOT_A(0, 0), 0, 0);
  STAGE(Abase, SLOT_A(0, 1), 1, 0);
  STAGE(Bbase, SLOT_B(0, 0), 0, 0);
  STAGE(Bbase, SLOT_B(0, 1), 1, 0);
  STAGE(Abase, SLOT_A(1, 0), 0, 1);
  STAGE(Bbase, SLOT_B(1, 0), 0, 1);
  STAGE(Bbase, SLOT_B(1, 1), 1, 1);
  asm volatile("s_waitcnt vmcnt(6)");   // tile 0 (oldest 8 loads) complete
  __builtin_amdgcn_s_barrier();

  for (int tt = 0; tt < nt; tt += 2) {
    TILE_BODY(tt, 0, 1);
    TILE_BODY(tt + 1, 1, 0);
  }

  // epilogue: C/D layout col = lane&15, row = quad*4 + reg (m89-verified)
  const float s = scale[0];
#pragma unroll
  for (int qm = 0; qm < 2; ++qm)
#pragma unroll
    for (int mf = 0; mf < 4; ++mf) {
      const int row0 = by * 256 + qm * 128 + wr * 64 + mf * 16 + quad * 4;
#pragma unroll
      for (int qn = 0; qn < 2; ++qn)
#pragma unroll
        for (int nf = 0; nf < 2; ++nf) {
          const int col = bx * 256 + qn * 128 + wc * 32 + nf * 16 + fr;
          const float bv = bias[col];
          float* cp = C + (size_t)row0 * N + col;
#pragma unroll
          for (int r = 0; r < 4; ++r)
            cp[(size_t)r * N] = s * acc[qm][qn][mf][nf][r] + bv;
        }
    }
}

// ---------------- launch ----------------

extern "C" void kernel_launch(void* const* d_in, const int* in_sizes, int n_in,
                              void* d_out, int out_size, void* d_ws, size_t ws_size,
                              hipStream_t stream) {
  const int M = 8192, N = 4096, K = 4096;

  const float* x    = (const float*)d_in[0];
  const int*   qw   = (const int*)d_in[1];
  const int*   zp   = (const int*)d_in[2];
  const float* sc   = (const float*)d_in[3];
  const float* bias = (const float*)d_in[4];
  float* out = (float*)d_out;

  __bf16* x_bf = (__bf16*)d_ws;
  __bf16* w_bf = (__bf16*)((char*)d_ws + (size_t)M * K * sizeof(__bf16));

  {
    int n8 = (M * K) / 8;
    cvt_x_bf16<<<n8 / 256, 256, 0, stream>>>((const float4*)x, (uint4*)x_bf, n8);
  }
  {
    int n8 = (N * K) / 8;
    cvt_w_bf16<<<n8 / 256, 256, 0, stream>>>((const int4*)qw, zp, (uint4*)w_bf, n8);
  }

  static bool attr_set = false;
  if (!attr_set) {
    hipFuncSetAttribute((const void*)gemm256,
                        hipFuncAttributeMaxDynamicSharedMemorySize, 131072);
    attr_set = true;
  }
  gemm256<<<dim3(512), dim3(512), 131072, stream>>>(x_bf, w_bf, sc, bias, out);
}